// Round 4
// baseline (1802.430 us; speedup 1.0000x reference)
//
#include <hip/hip_runtime.h>
#include <math.h>

#define NNODES 50000
#define NEDGES 800000
#define HDIM 128
#define NINV 32
#define K1 288
#define NTILE_E 50000     // 16-edge tiles (exact)
#define NTILE_N 3125      // 16-node tiles (exact)

#define W1S 296   // u16 stride, 148 dw = 20 mod 32 -> standard conflict-free b128 class
#define W2S 136   // 68 dw = 4 mod 32 -> same class
#define U1S 264
#define HCS 40    // h-chunk row stride u16 (20 dw)

typedef float floatx4 __attribute__((ext_vector_type(4)));
typedef short short8  __attribute__((ext_vector_type(8)));
union U4S8 { uint4 u; short8 s; };

__device__ __forceinline__ float silu_f(float z) { return z / (1.0f + __expf(-z)); }
__device__ __forceinline__ unsigned rnd_bf(float f) {
    unsigned u = __float_as_uint(f);
    return u + 0x7fffu + ((u >> 16) & 1u);            // RNE in the high 16
}
__device__ __forceinline__ unsigned short bf_rne(float f) { return (unsigned short)(rnd_bf(f) >> 16); }
__device__ __forceinline__ unsigned pk2(unsigned rlo, unsigned rhi) {
    return __builtin_amdgcn_perm(rhi, rlo, 0x07060302);   // lo16=hi16(rlo), hi16=hi16(rhi)
}
__device__ __forceinline__ short8 cvt8_rne(float4 a, float4 b) {
    U4S8 v;
    v.u.x = pk2(rnd_bf(a.x), rnd_bf(a.y));
    v.u.y = pk2(rnd_bf(a.z), rnd_bf(a.w));
    v.u.z = pk2(rnd_bf(b.x), rnd_bf(b.y));
    v.u.w = pk2(rnd_bf(b.z), rnd_bf(b.w));
    return v.s;
}

__device__ __forceinline__ int adj_at(const void* adj, int is64, long long pos) {
    if (is64) return (int)((const long long*)adj)[pos];
    return ((const int*)adj)[pos];
}

__global__ __launch_bounds__(256) void detect_idx64(const int* __restrict__ adj32,
                                                    int* __restrict__ flag) {
    __shared__ int any_nz;
    if (threadIdx.x == 0) any_nz = 0;
    __syncthreads();
    int v = adj32[threadIdx.x * 2 + 1];
    if (v != 0) atomicOr(&any_nz, 1);
    __syncthreads();
    if (threadIdx.x == 0) *flag = (any_nz == 0) ? 1 : 0;
}

__global__ __launch_bounds__(256) void prep_weights(
    const float* __restrict__ Wm1, const float* __restrict__ Wm2,
    const float* __restrict__ Wu1, const float* __restrict__ Wu2,
    unsigned short* __restrict__ Wm1t, unsigned short* __restrict__ Wm2t,
    unsigned short* __restrict__ Wu1t, unsigned short* __restrict__ Wu2t)
{
    int i = blockIdx.x * 256 + threadIdx.x;
    if (i < 128 * K1) {
        int n = i / K1, k = i % K1;
        Wm1t[i] = bf_rne(Wm1[k * HDIM + n]);
    } else if ((i -= 128 * K1) < 128 * HDIM) {
        int n = i / HDIM, k = i % HDIM;
        Wm2t[i] = bf_rne(Wm2[k * HDIM + n]);
    } else if ((i -= 128 * HDIM) < 128 * 256) {
        int n = i / 256, k = i % 256;
        Wu1t[i] = bf_rne(Wu1[k * HDIM + n]);
    } else if ((i -= 128 * 256) < 128 * HDIM) {
        int n = i / HDIM, k = i % HDIM;
        Wu2t[i] = bf_rne(Wu2[k * HDIM + n]);
    }
}

// fp32 -> bf16 (RNE), float4 granularity; count = #float4
__global__ __launch_bounds__(256) void cvt_f32_bf16(const float* __restrict__ src,
                                                    unsigned short* __restrict__ dst) {
    int i = blockIdx.x * 256 + threadIdx.x;
    float4 v = ((const float4*)src)[i];
    ushort4 o;
    o.x = bf_rne(v.x); o.y = bf_rne(v.y); o.z = bf_rne(v.z); o.w = bf_rne(v.w);
    ((ushort4*)dst)[i] = o;
}

#define MF8W1(aa) { _Pragma("unroll") for (int nt = 0; nt < 8; ++nt) { \
    short8 bb = *(const short8*)(wb1 + nt * 16 * W1S); \
    acc[nt] = __builtin_amdgcn_mfma_f32_16x16x32_bf16(aa, bb, acc[nt], 0, 0, 0); } }

#define LDW(off, col) (*(const uint4*)(xb + (off) + (col) * 32 + quad * 8))

#define WRCH(k) { unsigned short* hb = hc + (((k) & 1) ? 640 : 0); \
    _Pragma("unroll") for (int j = 0; j < 2; ++j) \
    _Pragma("unroll") for (int r = 0; r < 4; ++r) \
        hb[(quad * 4 + r) * HCS + j * 16 + l15] = bf_rne(silu_f(acc[2 * (k) + j][r])); }

// ------------- Edge kernel: persistent, 16 waves/CU, barrier-free K-loop -------------
__global__ __launch_bounds__(1024, 4) void edge_kernel(
    const unsigned short* __restrict__ xb, const void* __restrict__ adj,
    const int* __restrict__ flagp, const float* __restrict__ inv,
    const unsigned short* __restrict__ Wm1t, const float* __restrict__ bm1,
    const unsigned short* __restrict__ Wm2t, const float* __restrict__ bm2,
    const float* __restrict__ We, const float* __restrict__ be,
    float* __restrict__ aggr)
{
    __shared__ unsigned short s_w1[128 * W1S];   // 75,776 B
    __shared__ unsigned short s_w2[128 * W2S];   // 34,816 B
    __shared__ unsigned short s_hc[16 * 1280];   // 40,960 B (16 waves x dbuf x 16 x HCS)

    const int t    = threadIdx.x;
    const int is64 = *flagp;
    const int l    = t & 63;
    const int wid  = t >> 6;
    const int l15  = l & 15;
    const int quad = l >> 4;

    for (int idx = t; idx < 128 * 36; idx += 1024) {
        int n = idx / 36, c = idx % 36;
        *(uint4*)&s_w1[n * W1S + c * 8] = *(const uint4*)(Wm1t + n * K1 + c * 8);
    }
    for (int idx = t; idx < 128 * 16; idx += 1024) {
        int n = idx / 16, c = idx % 16;
        *(uint4*)&s_w2[n * W2S + c * 8] = *(const uint4*)(Wm2t + n * HDIM + c * 8);
    }

    // loop-invariant per-lane params
    float bm1v[8], bm2v[8], Wev[8];
    #pragma unroll
    for (int nt = 0; nt < 8; ++nt) {
        bm1v[nt] = bm1[nt * 16 + l15];
        bm2v[nt] = bm2[nt * 16 + l15];
        Wev[nt]  = We[nt * 16 + l15];
    }
    const float be0 = be[0];

    __syncthreads();   // only barrier

    unsigned short* hc = s_hc + wid * 1280;
    const int nwav = gridDim.x * 16;
    int tile = blockIdx.x * 16 + wid;

    // preamble: first tile's indices + A-steps 0..2 + inv
    int se = adj_at(adj, is64, (long long)tile * 16 + l15);
    int re = adj_at(adj, is64, (long long)NEDGES + tile * 16 + l15);
    unsigned oS = (unsigned)se * HDIM, oR = (unsigned)re * HDIM;
    uint4 P0 = LDW(oS, 0), P1 = LDW(oS, 1), P2 = LDW(oS, 2);
    float4 Pi0, Pi1;
    {
        const float* ip = inv + (long long)(tile * 16 + l15) * NINV + quad * 8;
        Pi0 = ((const float4*)ip)[0]; Pi1 = ((const float4*)ip)[1];
    }

    for (; tile < NTILE_E; tile += nwav) {
        const int next = tile + nwav;
        const int ne0  = (next < NTILE_E ? next : 0) * 16;
        int nse = adj_at(adj, is64, ne0 + l15);
        int nre = adj_at(adj, is64, (long long)NEDGES + ne0 + l15);
        unsigned noS, noR;

        floatx4 acc[8];
        #pragma unroll
        for (int nt = 0; nt < 8; ++nt)
            acc[nt] = (floatx4){bm1v[nt], bm1v[nt], bm1v[nt], bm1v[nt]};

        // ---- Layer 1: 9 K-steps; prefetch rolls into the NEXT tile at s>=5 ----
        {
            U4S8 c; short8 a;
            const unsigned short* wb1;
            c.u = P0; a = c.s; P0 = LDW(oS, 3); wb1 = s_w1 + l15 * W1S + 0 * 32 + quad * 8; MF8W1(a);
            c.u = P1; a = c.s; P1 = LDW(oR, 0); wb1 = s_w1 + l15 * W1S + 1 * 32 + quad * 8; MF8W1(a);
            c.u = P2; a = c.s; P2 = LDW(oR, 1); wb1 = s_w1 + l15 * W1S + 2 * 32 + quad * 8; MF8W1(a);
            c.u = P0; a = c.s; P0 = LDW(oR, 2); wb1 = s_w1 + l15 * W1S + 3 * 32 + quad * 8; MF8W1(a);
            c.u = P1; a = c.s; P1 = LDW(oR, 3); wb1 = s_w1 + l15 * W1S + 4 * 32 + quad * 8; MF8W1(a);
            noS = (unsigned)nse * HDIM; noR = (unsigned)nre * HDIM;
            c.u = P2; a = c.s; P2 = LDW(noS, 0); wb1 = s_w1 + l15 * W1S + 5 * 32 + quad * 8; MF8W1(a);
            c.u = P0; a = c.s; P0 = LDW(noS, 1); wb1 = s_w1 + l15 * W1S + 6 * 32 + quad * 8; MF8W1(a);
            c.u = P1; a = c.s; P1 = LDW(noS, 2); wb1 = s_w1 + l15 * W1S + 7 * 32 + quad * 8; MF8W1(a);
            a = cvt8_rne(Pi0, Pi1);
            {
                const float* ip = inv + (long long)(ne0 + l15) * NINV + quad * 8;
                Pi0 = ((const float4*)ip)[0]; Pi1 = ((const float4*)ip)[1];
            }
            wb1 = s_w1 + l15 * W1S + 8 * 32 + quad * 8; MF8W1(a);
        }

        // ---- Layer 2: chunked h double-buffer, wave-private (lgkmcnt-only sync) ----
        floatx4 acc2[8];
        #pragma unroll
        for (int nt = 0; nt < 8; ++nt)
            acc2[nt] = (floatx4){bm2v[nt], bm2v[nt], bm2v[nt], bm2v[nt]};

        WRCH(0);
        #pragma unroll
        for (int ks = 0; ks < 4; ++ks) {
            if (ks == 0) WRCH(1);
            if (ks == 1) WRCH(2);
            if (ks == 2) WRCH(3);
            U4S8 av; av.u = *(const uint4*)(hc + ((ks & 1) ? 640 : 0) + l15 * HCS + quad * 8);
            short8 a2 = av.s;
            #pragma unroll
            for (int nt = 0; nt < 8; ++nt) {
                short8 bb = *(const short8*)(s_w2 + (nt * 16 + l15) * W2S + ks * 32 + quad * 8);
                acc2[nt] = __builtin_amdgcn_mfma_f32_16x16x32_bf16(a2, bb, acc2[nt], 0, 0, 0);
            }
        }

        // ---- Epilogue: SiLU, gate, fp32 atomic scatter (next-tile loads already in flight) ----
        #pragma unroll
        for (int nt = 0; nt < 8; ++nt)
            #pragma unroll
            for (int r = 0; r < 4; ++r)
                acc2[nt][r] = silu_f(acc2[nt][r]);

        #pragma unroll
        for (int r = 0; r < 4; ++r) {
            float part = 0.f;
            #pragma unroll
            for (int nt = 0; nt < 8; ++nt) part = fmaf(acc2[nt][r], Wev[nt], part);
            part += __shfl_xor(part, 1);
            part += __shfl_xor(part, 2);
            part += __shfl_xor(part, 4);
            part += __shfl_xor(part, 8);
            float g = 1.0f / (1.0f + __expf(-(part + be0)));
            int rr = __shfl(re, quad * 4 + r, 16);
            float* dst = aggr + (long long)rr * HDIM + l15;
            #pragma unroll
            for (int nt = 0; nt < 8; ++nt)
                atomicAdd(dst + nt * 16, acc2[nt][r] * g);
        }

        // rotate next-tile state into place (P2,P0,P1 hold new steps 0,1,2)
        uint4 tmp = P2; P2 = P1; P1 = P0; P0 = tmp;
        oS = noS; oR = noR; re = nre;
    }
}

// ------------- Node kernel: 16-node tiles, chunked L2, residual epilogue -------------
__global__ __launch_bounds__(512) void node_kernel(
    const float* __restrict__ x, const unsigned short* __restrict__ xb,
    const unsigned short* __restrict__ aggrb,
    const unsigned short* __restrict__ Wu1t, const float* __restrict__ bu1,
    const unsigned short* __restrict__ Wu2t, const float* __restrict__ bu2,
    float* __restrict__ out)
{
    __shared__ unsigned short s_u1[128 * U1S];   // 67,584 B
    __shared__ unsigned short s_w2[128 * W2S];   // 34,816 B
    __shared__ unsigned short s_hc[8 * 1280];    // 20,480 B

    const int t    = threadIdx.x;
    const int l    = t & 63;
    const int wid  = t >> 6;
    const int l15  = l & 15;
    const int quad = l >> 4;

    for (int idx = t; idx < 128 * 32; idx += 512) {
        int n = idx / 32, c = idx % 32;
        *(uint4*)&s_u1[n * U1S + c * 8] = *(const uint4*)(Wu1t + n * 256 + c * 8);
    }
    for (int idx = t; idx < 128 * 16; idx += 512) {
        int n = idx / 16, c = idx % 16;
        *(uint4*)&s_w2[n * W2S + c * 8] = *(const uint4*)(Wu2t + n * HDIM + c * 8);
    }

    float bu1v[8], bu2v[8];
    #pragma unroll
    for (int nt = 0; nt < 8; ++nt) {
        bu1v[nt] = bu1[nt * 16 + l15];
        bu2v[nt] = bu2[nt * 16 + l15];
    }

    __syncthreads();

    const int tile = blockIdx.x * 8 + wid;
    if (tile >= NTILE_N) return;
    const int n0 = tile * 16;
    const unsigned oX = (unsigned)(n0 + l15) * HDIM;

    uint4 A[8];
    #pragma unroll
    for (int s = 0; s < 4; ++s) A[s]     = *(const uint4*)(xb    + oX + s * 32 + quad * 8);
    #pragma unroll
    for (int s = 0; s < 4; ++s) A[s + 4] = *(const uint4*)(aggrb + oX + s * 32 + quad * 8);

    floatx4 acc[8];
    #pragma unroll
    for (int nt = 0; nt < 8; ++nt)
        acc[nt] = (floatx4){bu1v[nt], bu1v[nt], bu1v[nt], bu1v[nt]};

    #pragma unroll
    for (int s = 0; s < 8; ++s) {
        U4S8 c; c.u = A[s]; short8 a = c.s;
        const unsigned short* wb = s_u1 + l15 * U1S + s * 32 + quad * 8;
        #pragma unroll
        for (int nt = 0; nt < 8; ++nt) {
            short8 bb = *(const short8*)(wb + nt * 16 * U1S);
            acc[nt] = __builtin_amdgcn_mfma_f32_16x16x32_bf16(a, bb, acc[nt], 0, 0, 0);
        }
    }

    floatx4 acc2[8];
    #pragma unroll
    for (int nt = 0; nt < 8; ++nt)
        acc2[nt] = (floatx4){bu2v[nt], bu2v[nt], bu2v[nt], bu2v[nt]};

    unsigned short* hc = s_hc + wid * 1280;
    WRCH(0);
    #pragma unroll
    for (int ks = 0; ks < 4; ++ks) {
        if (ks == 0) WRCH(1);
        if (ks == 1) WRCH(2);
        if (ks == 2) WRCH(3);
        U4S8 av; av.u = *(const uint4*)(hc + ((ks & 1) ? 640 : 0) + l15 * HCS + quad * 8);
        short8 a2 = av.s;
        #pragma unroll
        for (int nt = 0; nt < 8; ++nt) {
            short8 bb = *(const short8*)(s_w2 + (nt * 16 + l15) * W2S + ks * 32 + quad * 8);
            acc2[nt] = __builtin_amdgcn_mfma_f32_16x16x32_bf16(a2, bb, acc2[nt], 0, 0, 0);
        }
    }

    #pragma unroll
    for (int r = 0; r < 4; ++r) {
        int row = n0 + quad * 4 + r;
        const float* xr = x + (long long)row * HDIM + l15;
        float* orow = out + (long long)row * HDIM + l15;
        #pragma unroll
        for (int nt = 0; nt < 8; ++nt)
            orow[nt * 16] = xr[nt * 16] + acc2[nt][r];
    }
}

extern "C" void kernel_launch(void* const* d_in, const int* in_sizes, int n_in,
                              void* d_out, int out_size, void* d_ws, size_t ws_size,
                              hipStream_t stream)
{
    const float* x   = (const float*)d_in[0];
    const void*  adj = d_in[1];
    const float* inv = (const float*)d_in[2];
    const float* Wm1 = (const float*)d_in[3];
    const float* bm1 = (const float*)d_in[4];
    const float* Wm2 = (const float*)d_in[5];
    const float* bm2 = (const float*)d_in[6];
    const float* We  = (const float*)d_in[7];
    const float* be  = (const float*)d_in[8];
    const float* Wu1 = (const float*)d_in[9];
    const float* bu1 = (const float*)d_in[10];
    const float* Wu2 = (const float*)d_in[11];
    const float* bu2 = (const float*)d_in[12];
    float* out = (float*)d_out;

    char* ws = (char*)d_ws;
    size_t off = 0;
    float* aggr = (float*)(ws + off);                 off += (size_t)NNODES * HDIM * 4;   // 25,600,000
    int* flag = (int*)(ws + off);                     off += 16;
    unsigned short* Wm1t = (unsigned short*)(ws + off); off += 128 * K1 * 2;
    unsigned short* Wm2t = (unsigned short*)(ws + off); off += 128 * HDIM * 2;
    unsigned short* Wu1t = (unsigned short*)(ws + off); off += 128 * 256 * 2;
    unsigned short* Wu2t = (unsigned short*)(ws + off); off += 128 * HDIM * 2;
    unsigned short* xb    = (unsigned short*)(ws + off); off += (size_t)NNODES * HDIM * 2; // 12,800,000
    unsigned short* aggrb = (unsigned short*)(ws + off);                                   // 12,800,000

    hipMemsetAsync(aggr, 0, (size_t)NNODES * HDIM * sizeof(float), stream);
    detect_idx64<<<1, 256, 0, stream>>>((const int*)adj, flag);
    prep_weights<<<400, 256, 0, stream>>>(Wm1, Wm2, Wu1, Wu2, Wm1t, Wm2t, Wu1t, Wu2t);
    cvt_f32_bf16<<<NNODES * HDIM / 4 / 256, 256, 0, stream>>>(x, xb);
    edge_kernel<<<256, 1024, 0, stream>>>(xb, adj, flag, inv,
                                          Wm1t, bm1, Wm2t, bm2, We, be, aggr);
    cvt_f32_bf16<<<NNODES * HDIM / 4 / 256, 256, 0, stream>>>(aggr, aggrb);
    node_kernel<<<(NTILE_N + 7) / 8, 512, 0, stream>>>(x, xb, aggrb,
                                                       Wu1t, bu1, Wu2t, bu2, out);
}

// Round 5
// 1040.341 us; speedup vs baseline: 1.7325x; 1.7325x over previous
//
#include <hip/hip_runtime.h>
#include <math.h>

#define NNODES 50000
#define NEDGES 800000
#define HDIM 128
#define NINV 32
#define K1 288
#define NTILE_E 25000     // 32-edge tiles (exact)
#define NTILE_N 3125      // 16-node tiles (exact)

#define HES 136   // edge h row stride u16 (128+8): 68 dw -> 4*l15 bank phase, 16B aligned
#define U1S 264   // node Wu1 LDS stride
#define W2S 136   // node Wu2 LDS stride
#define HCS 40    // node h-chunk row stride

typedef float floatx4 __attribute__((ext_vector_type(4)));
typedef short short8  __attribute__((ext_vector_type(8)));
union U4S8 { uint4 u; short8 s; };

__device__ __forceinline__ float silu_f(float z) { return z / (1.0f + __expf(-z)); }
__device__ __forceinline__ unsigned rnd_bf(float f) {
    unsigned u = __float_as_uint(f);
    return u + 0x7fffu + ((u >> 16) & 1u);            // RNE in the high 16
}
__device__ __forceinline__ unsigned short bf_rne(float f) { return (unsigned short)(rnd_bf(f) >> 16); }
__device__ __forceinline__ unsigned pk2(unsigned rlo, unsigned rhi) {
    return __builtin_amdgcn_perm(rhi, rlo, 0x07060302);
}
__device__ __forceinline__ short8 cvt8_rne(float4 a, float4 b) {
    U4S8 v;
    v.u.x = pk2(rnd_bf(a.x), rnd_bf(a.y));
    v.u.y = pk2(rnd_bf(a.z), rnd_bf(a.w));
    v.u.z = pk2(rnd_bf(b.x), rnd_bf(b.y));
    v.u.w = pk2(rnd_bf(b.z), rnd_bf(b.w));
    return v.s;
}

__device__ __forceinline__ int adj_at(const void* adj, int is64, long long pos) {
    if (is64) return (int)((const long long*)adj)[pos];
    return ((const int*)adj)[pos];
}

__global__ __launch_bounds__(256) void detect_idx64(const int* __restrict__ adj32,
                                                    int* __restrict__ flag) {
    __shared__ int any_nz;
    if (threadIdx.x == 0) any_nz = 0;
    __syncthreads();
    int v = adj32[threadIdx.x * 2 + 1];
    if (v != 0) atomicOr(&any_nz, 1);
    __syncthreads();
    if (threadIdx.x == 0) *flag = (any_nz == 0) ? 1 : 0;
}

__global__ __launch_bounds__(256) void prep_weights(
    const float* __restrict__ Wm1, const float* __restrict__ Wm2,
    const float* __restrict__ Wu1, const float* __restrict__ Wu2,
    unsigned short* __restrict__ Wm1t, unsigned short* __restrict__ Wm2t,
    unsigned short* __restrict__ Wu1t, unsigned short* __restrict__ Wu2t)
{
    int i = blockIdx.x * 256 + threadIdx.x;
    if (i < 128 * K1) {
        int n = i / K1, k = i % K1;
        Wm1t[i] = bf_rne(Wm1[k * HDIM + n]);
    } else if ((i -= 128 * K1) < 128 * HDIM) {
        int n = i / HDIM, k = i % HDIM;
        Wm2t[i] = bf_rne(Wm2[k * HDIM + n]);
    } else if ((i -= 128 * HDIM) < 128 * 256) {
        int n = i / 256, k = i % 256;
        Wu1t[i] = bf_rne(Wu1[k * HDIM + n]);
    } else if ((i -= 128 * 256) < 128 * HDIM) {
        int n = i / HDIM, k = i % HDIM;
        Wu2t[i] = bf_rne(Wu2[k * HDIM + n]);
    }
}

__global__ __launch_bounds__(256) void cvt_f32_bf16(const float* __restrict__ src,
                                                    unsigned short* __restrict__ dst) {
    int i = blockIdx.x * 256 + threadIdx.x;
    float4 v = ((const float4*)src)[i];
    ushort4 o;
    o.x = bf_rne(v.x); o.y = bf_rne(v.y); o.z = bf_rne(v.z); o.w = bf_rne(v.w);
    ((ushort4*)dst)[i] = o;
}

// ---------- Edge kernel: 256 thr, 3 blocks/CU, NO weight LDS, NO barriers ----------
__global__ __launch_bounds__(256, 3) void edge_kernel(
    const unsigned short* __restrict__ xb, const void* __restrict__ adj,
    const int* __restrict__ flagp, const float* __restrict__ inv,
    const unsigned short* __restrict__ Wm1t, const float* __restrict__ bm1,
    const unsigned short* __restrict__ Wm2t, const float* __restrict__ bm2,
    const float* __restrict__ We, const float* __restrict__ be,
    float* __restrict__ aggr)
{
    __shared__ unsigned short s_h[4 * 32 * HES];   // 34,816 B: per-wave full h (32x128)

    const int t    = threadIdx.x;
    const int is64 = *flagp;
    const int l    = t & 63;
    const int wid  = t >> 6;
    const int l15  = l & 15;
    const int quad = l >> 4;
    unsigned short* hw = s_h + wid * (32 * HES);

    const float be0 = be[0];
    const int nwav = gridDim.x * 4;
    int tile = blockIdx.x * 4 + wid;

    int nse[2], nre[2];
    #pragma unroll
    for (int m = 0; m < 2; ++m) {
        nse[m] = adj_at(adj, is64, (long long)tile * 32 + m * 16 + l15);
        nre[m] = adj_at(adj, is64, (long long)NEDGES + (long long)tile * 32 + m * 16 + l15);
    }

    for (; tile < NTILE_E; tile += nwav) {
        const long long e0 = (long long)tile * 32;
        unsigned oS[2], oR[2];
        int re[2];
        #pragma unroll
        for (int m = 0; m < 2; ++m) {
            oS[m] = (unsigned)nse[m] * HDIM;
            oR[m] = (unsigned)nre[m] * HDIM;
            re[m] = nre[m];
        }

        auto asrc = [&](int s, int m) -> const unsigned short* {
            return (s < 4) ? (xb + oS[m] + s * 32 + quad * 8)
                           : (xb + oR[m] + (s - 4) * 32 + quad * 8);
        };

        uint4 PA[2][2];
        float4 PI[2][2];
        #pragma unroll
        for (int m = 0; m < 2; ++m) {
            PA[0][m] = *(const uint4*)asrc(0, m);
            PA[1][m] = *(const uint4*)asrc(1, m);
        }

        floatx4 acc[2][8];
        #pragma unroll
        for (int m = 0; m < 2; ++m)
            #pragma unroll
            for (int nt = 0; nt < 8; ++nt)
                acc[m][nt] = (floatx4){0.f, 0.f, 0.f, 0.f};

        // ---- Layer 1: 9 K-steps, B-fragments straight from global (L1/L2-hot) ----
        #pragma unroll
        for (int s = 0; s < 9; ++s) {
            short8 a[2];
            if (s < 8) {
                #pragma unroll
                for (int m = 0; m < 2; ++m) { U4S8 c; c.u = PA[s & 1][m]; a[m] = c.s; }
                if (s < 6) {
                    #pragma unroll
                    for (int m = 0; m < 2; ++m) PA[s & 1][m] = *(const uint4*)asrc(s + 2, m);
                }
            } else {
                #pragma unroll
                for (int m = 0; m < 2; ++m) a[m] = cvt8_rne(PI[m][0], PI[m][1]);
            }
            if (s == 5) {
                #pragma unroll
                for (int m = 0; m < 2; ++m) {
                    const float* ip = inv + (e0 + m * 16 + l15) * NINV + quad * 8;
                    PI[m][0] = ((const float4*)ip)[0];
                    PI[m][1] = ((const float4*)ip)[1];
                }
            }
            #pragma unroll
            for (int nt = 0; nt < 8; ++nt) {
                short8 b = *(const short8*)(Wm1t + (nt * 16 + l15) * K1 + s * 32 + quad * 8);
                acc[0][nt] = __builtin_amdgcn_mfma_f32_16x16x32_bf16(a[0], b, acc[0][nt], 0, 0, 0);
                acc[1][nt] = __builtin_amdgcn_mfma_f32_16x16x32_bf16(a[1], b, acc[1][nt], 0, 0, 0);
            }
        }

        // next-tile index prefetch (issued before the atomic storm)
        {
            int ntile = tile + nwav;
            long long ne = (ntile < NTILE_E ? (long long)ntile : 0) * 32;
            #pragma unroll
            for (int m = 0; m < 2; ++m) {
                nse[m] = adj_at(adj, is64, ne + m * 16 + l15);
                nre[m] = adj_at(adj, is64, (long long)NEDGES + ne + m * 16 + l15);
            }
        }

        // ---- L1 epilogue: h = silu(acc + bm1) -> wave-private LDS (bias reloaded, L1-hot) ----
        #pragma unroll
        for (int nt = 0; nt < 8; ++nt) {
            float b1 = bm1[nt * 16 + l15];
            #pragma unroll
            for (int m = 0; m < 2; ++m)
                #pragma unroll
                for (int r = 0; r < 4; ++r)
                    hw[(m * 16 + quad * 4 + r) * HES + nt * 16 + l15] =
                        bf_rne(silu_f(acc[m][nt][r] + b1));
        }

        #pragma unroll
        for (int m = 0; m < 2; ++m)
            #pragma unroll
            for (int nt = 0; nt < 8; ++nt)
                acc[m][nt] = (floatx4){0.f, 0.f, 0.f, 0.f};

        // ---- Layer 2: 4 K-steps, A from wave-private LDS, B from global ----
        #pragma unroll
        for (int ks = 0; ks < 4; ++ks) {
            short8 a2[2];
            #pragma unroll
            for (int m = 0; m < 2; ++m) {
                U4S8 v;
                v.u = *(const uint4*)(hw + (m * 16 + l15) * HES + ks * 32 + quad * 8);
                a2[m] = v.s;
            }
            #pragma unroll
            for (int nt = 0; nt < 8; ++nt) {
                short8 b = *(const short8*)(Wm2t + (nt * 16 + l15) * HDIM + ks * 32 + quad * 8);
                acc[0][nt] = __builtin_amdgcn_mfma_f32_16x16x32_bf16(a2[0], b, acc[0][nt], 0, 0, 0);
                acc[1][nt] = __builtin_amdgcn_mfma_f32_16x16x32_bf16(a2[1], b, acc[1][nt], 0, 0, 0);
            }
        }

        // ---- Epilogue: msg = silu(acc + bm2); gate; fp32 atomic scatter ----
        #pragma unroll
        for (int nt = 0; nt < 8; ++nt) {
            float b2 = bm2[nt * 16 + l15];
            #pragma unroll
            for (int m = 0; m < 2; ++m)
                #pragma unroll
                for (int r = 0; r < 4; ++r)
                    acc[m][nt][r] = silu_f(acc[m][nt][r] + b2);
        }

        float Wev[8];
        #pragma unroll
        for (int nt = 0; nt < 8; ++nt) Wev[nt] = We[nt * 16 + l15];

        #pragma unroll
        for (int m = 0; m < 2; ++m) {
            #pragma unroll
            for (int r = 0; r < 4; ++r) {
                float part = 0.f;
                #pragma unroll
                for (int nt = 0; nt < 8; ++nt) part = fmaf(acc[m][nt][r], Wev[nt], part);
                part += __shfl_xor(part, 1);
                part += __shfl_xor(part, 2);
                part += __shfl_xor(part, 4);
                part += __shfl_xor(part, 8);
                float g = 1.0f / (1.0f + __expf(-(part + be0)));
                int rr = __shfl(re[m], quad * 4 + r, 16);
                float* dst = aggr + (long long)rr * HDIM + l15;
                #pragma unroll
                for (int nt = 0; nt < 8; ++nt)
                    atomicAdd(dst + nt * 16, acc[m][nt][r] * g);
            }
        }
    }
}

// ---------- Node kernel: 16-node tiles, LDS weights, fp32 aggr read ----------
__global__ __launch_bounds__(512) void node_kernel(
    const float* __restrict__ x, const unsigned short* __restrict__ xb,
    const float* __restrict__ aggr,
    const unsigned short* __restrict__ Wu1t, const float* __restrict__ bu1,
    const unsigned short* __restrict__ Wu2t, const float* __restrict__ bu2,
    float* __restrict__ out)
{
    __shared__ unsigned short s_u1[128 * U1S];   // 67,584 B
    __shared__ unsigned short s_w2[128 * W2S];   // 34,816 B
    __shared__ unsigned short s_hc[8 * 1280];    // 20,480 B

    const int t    = threadIdx.x;
    const int l    = t & 63;
    const int wid  = t >> 6;
    const int l15  = l & 15;
    const int quad = l >> 4;

    for (int idx = t; idx < 128 * 32; idx += 512) {
        int n = idx / 32, c = idx % 32;
        *(uint4*)&s_u1[n * U1S + c * 8] = *(const uint4*)(Wu1t + n * 256 + c * 8);
    }
    for (int idx = t; idx < 128 * 16; idx += 512) {
        int n = idx / 16, c = idx % 16;
        *(uint4*)&s_w2[n * W2S + c * 8] = *(const uint4*)(Wu2t + n * HDIM + c * 8);
    }

    float bu1v[8], bu2v[8];
    #pragma unroll
    for (int nt = 0; nt < 8; ++nt) {
        bu1v[nt] = bu1[nt * 16 + l15];
        bu2v[nt] = bu2[nt * 16 + l15];
    }

    __syncthreads();

    const int tile = blockIdx.x * 8 + wid;
    if (tile >= NTILE_N) return;
    const int n0 = tile * 16;
    const unsigned oX = (unsigned)(n0 + l15) * HDIM;

    uint4 A[8];
    #pragma unroll
    for (int s = 0; s < 4; ++s) A[s] = *(const uint4*)(xb + oX + s * 32 + quad * 8);
    #pragma unroll
    for (int s = 0; s < 4; ++s) {
        const float* ap = aggr + (long long)oX + s * 32 + quad * 8;
        U4S8 v;
        v.s = cvt8_rne(((const float4*)ap)[0], ((const float4*)ap)[1]);
        A[s + 4] = v.u;
    }

    floatx4 acc[8];
    #pragma unroll
    for (int nt = 0; nt < 8; ++nt)
        acc[nt] = (floatx4){bu1v[nt], bu1v[nt], bu1v[nt], bu1v[nt]};

    #pragma unroll
    for (int s = 0; s < 8; ++s) {
        U4S8 c; c.u = A[s]; short8 a = c.s;
        const unsigned short* wb = s_u1 + l15 * U1S + s * 32 + quad * 8;
        #pragma unroll
        for (int nt = 0; nt < 8; ++nt) {
            short8 bb = *(const short8*)(wb + nt * 16 * U1S);
            acc[nt] = __builtin_amdgcn_mfma_f32_16x16x32_bf16(a, bb, acc[nt], 0, 0, 0);
        }
    }

    floatx4 acc2[8];
    #pragma unroll
    for (int nt = 0; nt < 8; ++nt)
        acc2[nt] = (floatx4){bu2v[nt], bu2v[nt], bu2v[nt], bu2v[nt]};

    unsigned short* hc = s_hc + wid * 1280;
    #define WRCHN(k) { unsigned short* hb = hc + (((k) & 1) ? 640 : 0); \
        _Pragma("unroll") for (int j = 0; j < 2; ++j) \
        _Pragma("unroll") for (int r = 0; r < 4; ++r) \
            hb[(quad * 4 + r) * HCS + j * 16 + l15] = bf_rne(silu_f(acc[2 * (k) + j][r])); }

    WRCHN(0);
    #pragma unroll
    for (int ks = 0; ks < 4; ++ks) {
        if (ks == 0) WRCHN(1);
        if (ks == 1) WRCHN(2);
        if (ks == 2) WRCHN(3);
        U4S8 av; av.u = *(const uint4*)(hc + ((ks & 1) ? 640 : 0) + l15 * HCS + quad * 8);
        short8 a2 = av.s;
        #pragma unroll
        for (int nt = 0; nt < 8; ++nt) {
            short8 bb = *(const short8*)(s_w2 + (nt * 16 + l15) * W2S + ks * 32 + quad * 8);
            acc2[nt] = __builtin_amdgcn_mfma_f32_16x16x32_bf16(a2, bb, acc2[nt], 0, 0, 0);
        }
    }

    #pragma unroll
    for (int r = 0; r < 4; ++r) {
        int row = n0 + quad * 4 + r;
        const float* xr = x + (long long)row * HDIM + l15;
        float* orow = out + (long long)row * HDIM + l15;
        #pragma unroll
        for (int nt = 0; nt < 8; ++nt)
            orow[nt * 16] = xr[nt * 16] + acc2[nt][r];
    }
}

extern "C" void kernel_launch(void* const* d_in, const int* in_sizes, int n_in,
                              void* d_out, int out_size, void* d_ws, size_t ws_size,
                              hipStream_t stream)
{
    const float* x   = (const float*)d_in[0];
    const void*  adj = d_in[1];
    const float* inv = (const float*)d_in[2];
    const float* Wm1 = (const float*)d_in[3];
    const float* bm1 = (const float*)d_in[4];
    const float* Wm2 = (const float*)d_in[5];
    const float* bm2 = (const float*)d_in[6];
    const float* We  = (const float*)d_in[7];
    const float* be  = (const float*)d_in[8];
    const float* Wu1 = (const float*)d_in[9];
    const float* bu1 = (const float*)d_in[10];
    const float* Wu2 = (const float*)d_in[11];
    const float* bu2 = (const float*)d_in[12];
    float* out = (float*)d_out;

    char* ws = (char*)d_ws;
    size_t off = 0;
    float* aggr = (float*)(ws + off);                   off += (size_t)NNODES * HDIM * 4;
    int* flag = (int*)(ws + off);                       off += 16;
    unsigned short* Wm1t = (unsigned short*)(ws + off); off += 128 * K1 * 2;
    unsigned short* Wm2t = (unsigned short*)(ws + off); off += 128 * HDIM * 2;
    unsigned short* Wu1t = (unsigned short*)(ws + off); off += 128 * 256 * 2;
    unsigned short* Wu2t = (unsigned short*)(ws + off); off += 128 * HDIM * 2;
    unsigned short* xb   = (unsigned short*)(ws + off);

    hipMemsetAsync(aggr, 0, (size_t)NNODES * HDIM * sizeof(float), stream);
    detect_idx64<<<1, 256, 0, stream>>>((const int*)adj, flag);
    prep_weights<<<400, 256, 0, stream>>>(Wm1, Wm2, Wu1, Wu2, Wm1t, Wm2t, Wu1t, Wu2t);
    cvt_f32_bf16<<<NNODES * HDIM / 4 / 256, 256, 0, stream>>>(x, xb);
    edge_kernel<<<768, 256, 0, stream>>>(xb, adj, flag, inv,
                                         Wm1t, bm1, Wm2t, bm2, We, be, aggr);
    node_kernel<<<(NTILE_N + 7) / 8, 512, 0, stream>>>(x, xb, aggr,
                                                       Wu1t, bu1, Wu2t, bu2, out);
}